// Round 11
// baseline (364.283 us; speedup 1.0000x reference)
//
#include <hip/hip_runtime.h>

// out = Σ_i ChebConv_i(x), K=3, normalization=None, lambda_max=2 (scale=1).
// lhat(v)[r] = (deg[r]-1)*v[r] - Σ_{e:dst=r} w_e v[src_e]
// Tx1 = lhat(x); Tx2 = 2*lhat(Tx1) - x
// out = x@ΣW[i,0] + Σ_i (Tx1_i@W[i,1] + Tx2_i@W[i,2]) + Σ_i b_i
//
// Round 11: r10 profile shows spmv gathers pinned at ~3.8 TB/s beyond-L2
// (L3 random-gather ceiling; more MLP gave +8% only). Channel-slice the
// feature dim 128 -> 4 x 32ch: gather working set per slice-pass = N*64B
// = 3.2MB, L2-resident on every XCD -> gathers served at L2 BW. Layouts:
// xb[slice][N][32], tx{1,2}b[conv][slice][N][32]. spmv: 16 rows/wave x
// 4 lanes x 16B, slice-major group order (x-slice stays hot across convs).
// gemm A-frag kq == slice kq (k-groups of 32 ch) -> trivial remap.

#define CDIM 128
#define RANGE 512
#define RSH 9
#define MAXNR 128

typedef __attribute__((ext_vector_type(8))) short bf16x8;
typedef __attribute__((ext_vector_type(8))) unsigned short u16x8;
typedef __attribute__((ext_vector_type(4))) float f32x4;

__device__ __forceinline__ float b2f(unsigned short h) {
  return __uint_as_float((unsigned)h << 16);
}
__device__ __forceinline__ unsigned short f2b(float f) {
  unsigned u = __float_as_uint(f);
  return (unsigned short)((u + 0x7FFF + ((u >> 16) & 1)) >> 16);
}
__device__ __forceinline__ float blo(unsigned u) { return __uint_as_float(u << 16); }
__device__ __forceinline__ float bhi(unsigned u) { return __uint_as_float(u & 0xFFFF0000u); }
__device__ __forceinline__ unsigned pk(float lo, float hi) {
  return (unsigned)f2b(lo) | ((unsigned)f2b(hi) << 16);
}

// x (f32, [N][128]) -> xb (bf16, [4][N][32])
__global__ __launch_bounds__(256) void xcast_kernel(const float2* __restrict__ x,
    ushort2* __restrict__ xb, int N) {
  int gid = blockIdx.x * 256 + threadIdx.x;
  if (gid >= N * 64) return;
  int n = gid >> 6, ch2 = gid & 63;       // channel-pair index 0..63
  float2 v = x[gid];
  int slice = ch2 >> 4;                    // 16 pairs (32 ch) per slice
  int off = ch2 & 15;
  xb[((size_t)slice * N + n) * 16 + off] = make_ushort2(f2b(v.x), f2b(v.y));
}

// Wtb[s][n][k] (bf16, transposed weights) for the 1+2*NCv GEMM stages; bs = Σ b_i.
__global__ __launch_bounds__(256) void wcast_kernel(const float* __restrict__ W,
    const float* __restrict__ b, unsigned short* __restrict__ Wtb,
    float* __restrict__ bs, int KK, int NCv) {
  int p = blockIdx.x * 256 + threadIdx.x;
  const int stages = 1 + 2 * NCv;
  if (p < stages * CDIM * CDIM) {
    int s = p >> 14;
    int nk = p & 16383;
    int n = nk >> 7, k = nk & 127;
    float v;
    if (s == 0) {
      v = 0.f;
      for (int i = 0; i < NCv; ++i)
        v += W[(size_t)i * KK * CDIM * CDIM + (size_t)k * CDIM + n];
    } else {
      int i, kk;
      if (s & 1) { i = (s - 1) >> 1; kk = 1; }
      else       { i = (s >> 1) - 1; kk = 2; }
      v = W[(size_t)i * KK * CDIM * CDIM + (size_t)kk * CDIM * CDIM + (size_t)k * CDIM + n];
    }
    Wtb[p] = f2b(v);
  }
  if (p < CDIM) {
    float s = 0.f;
    for (int i = 0; i < NCv; ++i) s += b[i * CDIM + p];
    bs[p] = s;
  }
}

// coarse per-bucket counts of src and dst, LDS-aggregated
__global__ __launch_bounds__(256) void hist_coarse(const int* __restrict__ ei,
    int* __restrict__ coarse, int E, int NCv, int nr) {
  __shared__ int h[2 * MAXNR];
  int t = threadIdx.x;
  int g0 = blockIdx.x * 256 + t;
  int stride = gridDim.x * 256;
  for (int conv = 0; conv < NCv; ++conv) {
    if (t < 2 * MAXNR) h[t] = 0;
    __syncthreads();
    const int* srcv = ei + (size_t)conv * 2 * E;
    const int* dstv = srcv + E;
    for (int e = g0; e < E; e += stride) {
      atomicAdd(&h[srcv[e] >> RSH], 1);
      atomicAdd(&h[MAXNR + (dstv[e] >> RSH)], 1);
    }
    __syncthreads();
    if (t < nr) {
      if (h[t]) atomicAdd(&coarse[(conv * 2 + 0) * MAXNR + t], h[t]);
      if (h[MAXNR + t]) atomicAdd(&coarse[(conv * 2 + 1) * MAXNR + t], h[MAXNR + t]);
    }
    __syncthreads();
  }
}

// tiny serial scans: bases_d/s[conv][0..nr], cursors init = bases
__global__ __launch_bounds__(64) void scan_coarse(const int* __restrict__ coarse,
    int* __restrict__ bases_s, int* __restrict__ bases_d,
    int* __restrict__ cur_s, int* __restrict__ cur_d, int NCv, int nr) {
  int t = threadIdx.x;
  if (t >= NCv * 2) return;
  int conv = t >> 1, ax = t & 1;
  const int* c = coarse + (conv * 2 + ax) * MAXNR;
  int* bases = (ax ? bases_d : bases_s) + conv * (MAXNR + 1);
  int* cur = (ax ? cur_d : cur_s) + conv * MAXNR;
  int acc = 0;
  for (int b = 0; b < nr; ++b) {
    bases[b] = acc; cur[b] = acc; acc += c[b];
  }
  bases[nr] = acc;
}

// partition edges into node-range buckets (see r7/r8)
__global__ __launch_bounds__(256) void partition_kernel(const int* __restrict__ ei,
    const float* __restrict__ ew, int* __restrict__ cur_d, int* __restrict__ cur_s,
    ushort4* __restrict__ D, ushort2* __restrict__ S, int E, int CE, int P,
    int NCv, int nr) {
  __shared__ int ld[MAXNR], ls[MAXNR], cd[MAXNR], cs[MAXNR];
  int conv = blockIdx.x / P;
  int pck = blockIdx.x - conv * P;
  int e0 = pck * CE;
  int e1 = min(E, e0 + CE);
  int t = threadIdx.x;
  const int* srcv = ei + (size_t)conv * 2 * E;
  const int* dstv = srcv + E;
  const float* w = ew + (size_t)conv * E;
  if (t < MAXNR) { ld[t] = 0; ls[t] = 0; }
  __syncthreads();
  for (int e = e0 + t; e < e1; e += 256) {
    atomicAdd(&ld[dstv[e] >> RSH], 1);
    atomicAdd(&ls[srcv[e] >> RSH], 1);
  }
  __syncthreads();
  if (t < nr) {
    cd[t] = ld[t] ? atomicAdd(&cur_d[conv * MAXNR + t], ld[t]) : 0;
    cs[t] = ls[t] ? atomicAdd(&cur_s[conv * MAXNR + t], ls[t]) : 0;
  }
  __syncthreads();
  ushort4* Dc = D + (size_t)conv * E;
  ushort2* Sc = S + (size_t)conv * E;
  for (int e = e0 + t; e < e1; e += 256) {
    int s = srcv[e], d = dstv[e];
    unsigned short wb = f2b(w[e]);
    int pd = atomicAdd(&cd[d >> RSH], 1);
    Dc[pd] = make_ushort4((unsigned short)s, (unsigned short)d, wb, 0);
    int ps = atomicAdd(&cs[s >> RSH], 1);
    Sc[ps] = make_ushort2((unsigned short)s, wb);
  }
}

// per (conv, bucket): LDS fine hist + deg; block scan; write row_ptr/diag/CSR.
__global__ __launch_bounds__(512) void finalize_kernel(const ushort4* __restrict__ D,
    const ushort2* __restrict__ S, const int* __restrict__ bases_d,
    const int* __restrict__ bases_s, int* __restrict__ row_ptr,
    float* __restrict__ diag, ushort2* __restrict__ srcw, int E, int N,
    int NCv, int nr) {
  __shared__ unsigned int hist[RANGE];
  __shared__ float fdeg[RANGE];
  __shared__ unsigned int wls[8];
  int conv = blockIdx.x / nr;
  int b = blockIdx.x - conv * nr;
  int t = threadIdx.x;
  hist[t] = 0u; fdeg[t] = 0.f;
  __syncthreads();
  int db0 = bases_d[conv * (MAXNR + 1) + b], db1 = bases_d[conv * (MAXNR + 1) + b + 1];
  int sb0 = bases_s[conv * (MAXNR + 1) + b], sb1 = bases_s[conv * (MAXNR + 1) + b + 1];
  const ushort4* Dc = D + (size_t)conv * E;
  const ushort2* Sc = S + (size_t)conv * E;
  for (int i = db0 + t; i < db1; i += 512)
    atomicAdd(&hist[Dc[i].y & (RANGE - 1)], 1u);
  for (int i = sb0 + t; i < sb1; i += 512) {
    ushort2 r = Sc[i];
    atomicAdd(&fdeg[r.x & (RANGE - 1)], b2f(r.y));
  }
  __syncthreads();
  unsigned int v = hist[t];
  int lane = t & 63, wid = t >> 6;
  unsigned int incl = v;
  #pragma unroll
  for (int off = 1; off < 64; off <<= 1) {
    unsigned int tmp = __shfl_up((int)incl, off, 64);
    if (lane >= off) incl += tmp;
  }
  if (lane == 63) wls[wid] = incl;
  __syncthreads();
  if (wid == 0) {
    unsigned int x = (lane < 8) ? wls[lane] : 0u;
    #pragma unroll
    for (int off = 1; off < 8; off <<= 1) {
      unsigned int tmp = __shfl_up((int)x, off, 64);
      if (lane >= off) x += tmp;
    }
    if (lane < 8) wls[lane] = x;
  }
  __syncthreads();
  unsigned int excl = (wid ? wls[wid - 1] : 0u) + (incl - v);
  hist[t] = excl;
  __syncthreads();
  int n0 = b << RSH;
  int* rp = row_ptr + (size_t)conv * (N + 1);
  float* dg = diag + (size_t)conv * N;
  int n = n0 + t;
  if (n < N) {
    rp[n] = db0 + (int)excl;
    dg[n] = fdeg[t] - 1.0f;
  }
  if (b == nr - 1 && t == 0) rp[N] = E;
  __syncthreads();
  ushort2* swc = srcw + (size_t)conv * E;
  for (int i = db0 + t; i < db1; i += 512) {
    ushort4 r = Dc[i];
    unsigned int pos = atomicAdd(&hist[r.y & (RANGE - 1)], 1u);
    swc[db0 + (int)pos] = make_ushort2(r.x, r.z);
  }
}

// Tx1 slice-pass: group = slice*NCv + conv (slice-major: x-slice stays hot
// across convs). 16 rows/wave, 4 lanes x 16B (8 ch) per row.
__global__ __launch_bounds__(256) void spmvA(const int* __restrict__ row_ptr,
    const ushort2* __restrict__ srcw, const float* __restrict__ diag,
    const unsigned short* __restrict__ xb, unsigned short* __restrict__ tx1b,
    int N, int E, int NCv, int BPG) {
  int grp = blockIdx.x / BPG;
  int bo = blockIdx.x - grp * BPG;
  int slice = grp / NCv;
  int conv = grp - slice * NCv;
  int t = threadIdx.x;
  int row = bo * 64 + (t >> 2);
  if (row >= N) return;
  int quad = t & 3;
  const int* rp = row_ptr + (size_t)conv * (N + 1);
  const ushort2* sw = srcw + (size_t)conv * E;
  const unsigned short* xs = xb + (size_t)slice * N * 32;
  float d = diag[(size_t)conv * N + row];
  uint4 xv = *(const uint4*)(xs + (size_t)row * 32 + quad * 8);
  float a0 = d * blo(xv.x), a1 = d * bhi(xv.x);
  float a2 = d * blo(xv.y), a3 = d * bhi(xv.y);
  float a4 = d * blo(xv.z), a5 = d * bhi(xv.z);
  float a6 = d * blo(xv.w), a7 = d * bhi(xv.w);
  int e = rp[row], end = rp[row + 1];
  for (; e + 3 < end; e += 4) {
    ushort2 s0 = sw[e], s1 = sw[e + 1], s2 = sw[e + 2], s3 = sw[e + 3];
    uint4 v0 = *(const uint4*)(xs + (size_t)s0.x * 32 + quad * 8);
    uint4 v1 = *(const uint4*)(xs + (size_t)s1.x * 32 + quad * 8);
    uint4 v2 = *(const uint4*)(xs + (size_t)s2.x * 32 + quad * 8);
    uint4 v3 = *(const uint4*)(xs + (size_t)s3.x * 32 + quad * 8);
    float w0 = -b2f(s0.y), w1 = -b2f(s1.y), w2 = -b2f(s2.y), w3 = -b2f(s3.y);
    a0 = fmaf(w0, blo(v0.x), a0); a1 = fmaf(w0, bhi(v0.x), a1);
    a2 = fmaf(w0, blo(v0.y), a2); a3 = fmaf(w0, bhi(v0.y), a3);
    a4 = fmaf(w0, blo(v0.z), a4); a5 = fmaf(w0, bhi(v0.z), a5);
    a6 = fmaf(w0, blo(v0.w), a6); a7 = fmaf(w0, bhi(v0.w), a7);
    a0 = fmaf(w1, blo(v1.x), a0); a1 = fmaf(w1, bhi(v1.x), a1);
    a2 = fmaf(w1, blo(v1.y), a2); a3 = fmaf(w1, bhi(v1.y), a3);
    a4 = fmaf(w1, blo(v1.z), a4); a5 = fmaf(w1, bhi(v1.z), a5);
    a6 = fmaf(w1, blo(v1.w), a6); a7 = fmaf(w1, bhi(v1.w), a7);
    a0 = fmaf(w2, blo(v2.x), a0); a1 = fmaf(w2, bhi(v2.x), a1);
    a2 = fmaf(w2, blo(v2.y), a2); a3 = fmaf(w2, bhi(v2.y), a3);
    a4 = fmaf(w2, blo(v2.z), a4); a5 = fmaf(w2, bhi(v2.z), a5);
    a6 = fmaf(w2, blo(v2.w), a6); a7 = fmaf(w2, bhi(v2.w), a7);
    a0 = fmaf(w3, blo(v3.x), a0); a1 = fmaf(w3, bhi(v3.x), a1);
    a2 = fmaf(w3, blo(v3.y), a2); a3 = fmaf(w3, bhi(v3.y), a3);
    a4 = fmaf(w3, blo(v3.z), a4); a5 = fmaf(w3, bhi(v3.z), a5);
    a6 = fmaf(w3, blo(v3.w), a6); a7 = fmaf(w3, bhi(v3.w), a7);
  }
  for (; e < end; ++e) {
    ushort2 s0 = sw[e];
    uint4 v0 = *(const uint4*)(xs + (size_t)s0.x * 32 + quad * 8);
    float w0 = -b2f(s0.y);
    a0 = fmaf(w0, blo(v0.x), a0); a1 = fmaf(w0, bhi(v0.x), a1);
    a2 = fmaf(w0, blo(v0.y), a2); a3 = fmaf(w0, bhi(v0.y), a3);
    a4 = fmaf(w0, blo(v0.z), a4); a5 = fmaf(w0, bhi(v0.z), a5);
    a6 = fmaf(w0, blo(v0.w), a6); a7 = fmaf(w0, bhi(v0.w), a7);
  }
  unsigned short* o = tx1b + ((size_t)conv * 4 + slice) * N * 32 +
                      (size_t)row * 32 + quad * 8;
  *(uint4*)o = make_uint4(pk(a0, a1), pk(a2, a3), pk(a4, a5), pk(a6, a7));
}

// Tx2 slice-pass: gathers from tx1[conv][slice], subtracts x[slice].
__global__ __launch_bounds__(256) void spmvB_all(const int* __restrict__ row_ptr,
    const ushort2* __restrict__ srcw, const float* __restrict__ diag,
    const unsigned short* __restrict__ t1all, const unsigned short* __restrict__ xb,
    unsigned short* __restrict__ t2all, int N, int E, int NCv, int BPG) {
  int grp = blockIdx.x / BPG;
  int bo = blockIdx.x - grp * BPG;
  int slice = grp / NCv;
  int conv = grp - slice * NCv;
  int t = threadIdx.x;
  int row = bo * 64 + (t >> 2);
  if (row >= N) return;
  int quad = t & 3;
  const int* rp = row_ptr + (size_t)conv * (N + 1);
  const ushort2* sw = srcw + (size_t)conv * E;
  const unsigned short* ts = t1all + ((size_t)conv * 4 + slice) * N * 32;
  const unsigned short* xs = xb + (size_t)slice * N * 32;
  float d = diag[(size_t)conv * N + row];
  uint4 tv = *(const uint4*)(ts + (size_t)row * 32 + quad * 8);
  float a0 = d * blo(tv.x), a1 = d * bhi(tv.x);
  float a2 = d * blo(tv.y), a3 = d * bhi(tv.y);
  float a4 = d * blo(tv.z), a5 = d * bhi(tv.z);
  float a6 = d * blo(tv.w), a7 = d * bhi(tv.w);
  int e = rp[row], end = rp[row + 1];
  for (; e + 3 < end; e += 4) {
    ushort2 s0 = sw[e], s1 = sw[e + 1], s2 = sw[e + 2], s3 = sw[e + 3];
    uint4 v0 = *(const uint4*)(ts + (size_t)s0.x * 32 + quad * 8);
    uint4 v1 = *(const uint4*)(ts + (size_t)s1.x * 32 + quad * 8);
    uint4 v2 = *(const uint4*)(ts + (size_t)s2.x * 32 + quad * 8);
    uint4 v3 = *(const uint4*)(ts + (size_t)s3.x * 32 + quad * 8);
    float w0 = -b2f(s0.y), w1 = -b2f(s1.y), w2 = -b2f(s2.y), w3 = -b2f(s3.y);
    a0 = fmaf(w0, blo(v0.x), a0); a1 = fmaf(w0, bhi(v0.x), a1);
    a2 = fmaf(w0, blo(v0.y), a2); a3 = fmaf(w0, bhi(v0.y), a3);
    a4 = fmaf(w0, blo(v0.z), a4); a5 = fmaf(w0, bhi(v0.z), a5);
    a6 = fmaf(w0, blo(v0.w), a6); a7 = fmaf(w0, bhi(v0.w), a7);
    a0 = fmaf(w1, blo(v1.x), a0); a1 = fmaf(w1, bhi(v1.x), a1);
    a2 = fmaf(w1, blo(v1.y), a2); a3 = fmaf(w1, bhi(v1.y), a3);
    a4 = fmaf(w1, blo(v1.z), a4); a5 = fmaf(w1, bhi(v1.z), a5);
    a6 = fmaf(w1, blo(v1.w), a6); a7 = fmaf(w1, bhi(v1.w), a7);
    a0 = fmaf(w2, blo(v2.x), a0); a1 = fmaf(w2, bhi(v2.x), a1);
    a2 = fmaf(w2, blo(v2.y), a2); a3 = fmaf(w2, bhi(v2.y), a3);
    a4 = fmaf(w2, blo(v2.z), a4); a5 = fmaf(w2, bhi(v2.z), a5);
    a6 = fmaf(w2, blo(v2.w), a6); a7 = fmaf(w2, bhi(v2.w), a7);
    a0 = fmaf(w3, blo(v3.x), a0); a1 = fmaf(w3, bhi(v3.x), a1);
    a2 = fmaf(w3, blo(v3.y), a2); a3 = fmaf(w3, bhi(v3.y), a3);
    a4 = fmaf(w3, blo(v3.z), a4); a5 = fmaf(w3, bhi(v3.z), a5);
    a6 = fmaf(w3, blo(v3.w), a6); a7 = fmaf(w3, bhi(v3.w), a7);
  }
  for (; e < end; ++e) {
    ushort2 s0 = sw[e];
    uint4 v0 = *(const uint4*)(ts + (size_t)s0.x * 32 + quad * 8);
    float w0 = -b2f(s0.y);
    a0 = fmaf(w0, blo(v0.x), a0); a1 = fmaf(w0, bhi(v0.x), a1);
    a2 = fmaf(w0, blo(v0.y), a2); a3 = fmaf(w0, bhi(v0.y), a3);
    a4 = fmaf(w0, blo(v0.z), a4); a5 = fmaf(w0, bhi(v0.z), a5);
    a6 = fmaf(w0, blo(v0.w), a6); a7 = fmaf(w0, bhi(v0.w), a7);
  }
  uint4 xv = *(const uint4*)(xs + (size_t)row * 32 + quad * 8);
  a0 = 2.f * a0 - blo(xv.x); a1 = 2.f * a1 - bhi(xv.x);
  a2 = 2.f * a2 - blo(xv.y); a3 = 2.f * a3 - bhi(xv.y);
  a4 = 2.f * a4 - blo(xv.z); a5 = 2.f * a5 - bhi(xv.z);
  a6 = 2.f * a6 - blo(xv.w); a7 = 2.f * a7 - bhi(xv.w);
  unsigned short* o = t2all + ((size_t)conv * 4 + slice) * N * 32 +
                      (size_t)row * 32 + quad * 8;
  *(uint4*)o = make_uint4(pk(a0, a1), pk(a2, a3), pk(a4, a5), pk(a6, a7));
}

// MFMA GEMM with LDS double-buffered B (r9 verified). A now sliced:
// fragment kq of stage s reads slice kq of that stage's operand.
__global__ __launch_bounds__(256) void gemm_mfma(const unsigned short* __restrict__ xb,
    const unsigned short* __restrict__ t1all, const unsigned short* __restrict__ t2all,
    const unsigned short* __restrict__ Wtb, const float* __restrict__ bs,
    float* __restrict__ C, int N, int NCv) {
  __shared__ unsigned short Bl[2][CDIM * CDIM];
  const int t = threadIdx.x;
  const int wid = t >> 6;
  const int lane = t & 63;
  const int lr = lane & 15;
  const int lk = lane >> 4;
  const int r0 = blockIdx.x * 64 + wid * 16;
  const int stages = 1 + 2 * NCv;

  const int srow0 = t >> 4;
  const int wslot = t & 15;
  const int gslot = (t & 15) ^ ((t >> 4) & 7);

  f32x4 acc[8];
  #pragma unroll
  for (int nt = 0; nt < 8; ++nt) acc[nt] = (f32x4){0.f, 0.f, 0.f, 0.f};

  int ra = r0 + lr;
  ra = ra < N ? ra : N - 1;

  auto aslice = [&](int s, int kq) -> const unsigned short* {
    if (s == 0) return xb + (size_t)kq * (size_t)N * 32;
    if (s & 1) return t1all + ((size_t)((s - 1) >> 1) * 4 + kq) * (size_t)N * 32;
    return t2all + ((size_t)((s >> 1) - 1) * 4 + kq) * (size_t)N * 32;
  };

  u16x8 stg[8];
  {
    const unsigned short* Ws = Wtb;
    #pragma unroll
    for (int i = 0; i < 8; ++i)
      stg[i] = *(const u16x8*)(Ws + (size_t)(srow0 + i * 16) * CDIM + gslot * 8);
    #pragma unroll
    for (int i = 0; i < 8; ++i)
      *(u16x8*)(&Bl[0][(srow0 + i * 16) * CDIM + wslot * 8]) = stg[i];
  }
  bf16x8 aC[4], aN[4];
  #pragma unroll
  for (int kq = 0; kq < 4; ++kq)
    aC[kq] = *(const bf16x8*)(aslice(0, kq) + (size_t)ra * 32 + lk * 8);

  for (int s = 0; s < stages; ++s) {
    const int nb = s & 1;
    if (s + 1 < stages) {
      const unsigned short* Ws = Wtb + (size_t)(s + 1) * CDIM * CDIM;
      #pragma unroll
      for (int i = 0; i < 8; ++i)
        stg[i] = *(const u16x8*)(Ws + (size_t)(srow0 + i * 16) * CDIM + gslot * 8);
      #pragma unroll
      for (int kq = 0; kq < 4; ++kq)
        aN[kq] = *(const bf16x8*)(aslice(s + 1, kq) + (size_t)ra * 32 + lk * 8);
    }
    __syncthreads();
    #pragma unroll
    for (int nt = 0; nt < 8; ++nt) {
      const int row = nt * 16 + lr;
      const unsigned short* Bb = &Bl[nb][row * CDIM];
      #pragma unroll
      for (int kq = 0; kq < 4; ++kq) {
        const bf16x8 bf = *(const bf16x8*)(Bb + (((kq * 4 + lk) ^ (lr & 7)) * 8));
        acc[nt] = __builtin_amdgcn_mfma_f32_16x16x32_bf16(aC[kq], bf, acc[nt], 0, 0, 0);
      }
    }
    if (s + 1 < stages) {
      #pragma unroll
      for (int i = 0; i < 8; ++i)
        *(u16x8*)(&Bl[nb ^ 1][(srow0 + i * 16) * CDIM + wslot * 8]) = stg[i];
      #pragma unroll
      for (int kq = 0; kq < 4; ++kq) aC[kq] = aN[kq];
    }
  }

  const int orow = r0 + lk * 4;
  #pragma unroll
  for (int nt = 0; nt < 8; ++nt) {
    int col = nt * 16 + lr;
    float bb = bs[col];
    #pragma unroll
    for (int reg = 0; reg < 4; ++reg) {
      int r = orow + reg;
      if (r < N) C[(size_t)r * CDIM + col] = acc[nt][reg] + bb;
    }
  }
}

extern "C" void kernel_launch(void* const* d_in, const int* in_sizes, int n_in,
                              void* d_out, int out_size, void* d_ws, size_t ws_size,
                              hipStream_t stream) {
  const float* x  = (const float*)d_in[0];
  const int*   ei = (const int*)d_in[1];    // [NC, 2, E] int32
  const float* ew = (const float*)d_in[2];  // [NC, E]
  const float* W  = (const float*)d_in[3];  // [NC, K, 128, 128]
  const float* b  = (const float*)d_in[4];  // [NC, 128]

  const int Nn  = in_sizes[0] / CDIM;
  const int NCv = in_sizes[4] / CDIM;
  const int E   = in_sizes[2] / NCv;
  const int KK  = in_sizes[3] / (NCv * CDIM * CDIM);
  const int stages = 1 + 2 * NCv;
  const int nr = (Nn + RANGE - 1) / RANGE;

  char* p = (char*)d_ws;
  auto take = [&](size_t bytes) { char* q = p; p += (bytes + 255) & ~(size_t)255; return q; };
  float* diag    = (float*)take((size_t)NCv * Nn * 4);
  int*   row_ptr = (int*)take((size_t)NCv * (Nn + 1) * 4);
  int*   coarse  = (int*)take((size_t)NCv * 2 * MAXNR * 4);
  int*   bases_s = (int*)take((size_t)NCv * (MAXNR + 1) * 4);
  int*   bases_d = (int*)take((size_t)NCv * (MAXNR + 1) * 4);
  int*   cur_s   = (int*)take((size_t)NCv * MAXNR * 4);
  int*   cur_d   = (int*)take((size_t)NCv * MAXNR * 4);
  unsigned short* Wtb = (unsigned short*)take((size_t)stages * CDIM * CDIM * 2);
  float* bs      = (float*)take(CDIM * 4);
  ushort2* xb    = (ushort2*)take((size_t)Nn * 64 * 4);      // [4][N][32] bf16
  ushort2* tx1b  = (ushort2*)take((size_t)NCv * Nn * 64 * 4); // [NC][4][N][32]
  size_t D_bytes  = ((size_t)NCv * E * 8 + 255) & ~(size_t)255;
  size_t S_bytes  = ((size_t)NCv * E * 4 + 255) & ~(size_t)255;
  size_t tx2_bytes = (size_t)NCv * Nn * 64 * 4;
  size_t big_bytes = D_bytes + S_bytes > tx2_bytes ? D_bytes + S_bytes : tx2_bytes;
  char* big = take(big_bytes);
  ushort2* tx2b = (ushort2*)big;
  ushort4* D    = (ushort4*)big;
  ushort2* S    = (ushort2*)(big + D_bytes);
  ushort2* srcw = (ushort2*)take((size_t)NCv * E * 4);

  hipMemsetAsync(coarse, 0, (size_t)NCv * 2 * MAXNR * 4, stream);

  xcast_kernel<<<(Nn * 64 + 255) / 256, 256, 0, stream>>>(
      (const float2*)x, xb, Nn);
  wcast_kernel<<<(stages * CDIM * CDIM + 255) / 256, 256, 0, stream>>>(
      W, b, Wtb, bs, KK, NCv);
  hist_coarse<<<512, 256, 0, stream>>>(ei, coarse, E, NCv, nr);
  scan_coarse<<<1, 64, 0, stream>>>(coarse, bases_s, bases_d, cur_s, cur_d, NCv, nr);

  const int P = 256;
  const int CE = (E + P - 1) / P;
  partition_kernel<<<NCv * P, 256, 0, stream>>>(ei, ew, cur_d, cur_s, D, S,
                                                E, CE, P, NCv, nr);
  finalize_kernel<<<NCv * nr, 512, 0, stream>>>(D, S, bases_d, bases_s,
                                                row_ptr, diag, srcw, E, Nn, NCv, nr);

  const int BPG = (Nn + 63) / 64;
  spmvA<<<4 * NCv * BPG, 256, 0, stream>>>(row_ptr, srcw, diag,
      (const unsigned short*)xb, (unsigned short*)tx1b, Nn, E, NCv, BPG);
  spmvB_all<<<4 * NCv * BPG, 256, 0, stream>>>(row_ptr, srcw, diag,
      (const unsigned short*)tx1b, (const unsigned short*)xb,
      (unsigned short*)tx2b, Nn, E, NCv, BPG);

  gemm_mfma<<<(Nn + 63) / 64, 256, 0, stream>>>(
      (const unsigned short*)xb, (const unsigned short*)tx1b,
      (const unsigned short*)tx2b, Wtb, bs, (float*)d_out, Nn, NCv);
}

// Round 13
// 306.305 us; speedup vs baseline: 1.1893x; 1.1893x over previous
//
#include <hip/hip_runtime.h>

// out = Σ_i ChebConv_i(x), K=3, normalization=None, lambda_max=2 (scale=1).
// lhat(v)[r] = (deg[r]-1)*v[r] - Σ_{e:dst=r} w_e v[src_e]
// Tx1 = lhat(x); Tx2 = 2*lhat(Tx1) - x
// out = x@ΣW[i,0] + Σ_i (Tx1_i@W[i,1] + Tx2_i@W[i,2]) + Σ_i b_i
//
// Round 13: r12 (hist-less fixed-capacity partition) with the crash fixed:
// cntD/cntS now share ONE allocation and are zeroed with one exact-size
// memset (r12 zeroed across take()'s 256B padding -> 26 poisoned counters ->
// OOB Sfix writes -> abort). spmv/gemm identical to r10 (best known).

#define CDIM 128
#define RANGE 512
#define RSH 9
#define MAXNR 128

typedef __attribute__((ext_vector_type(8))) short bf16x8;
typedef __attribute__((ext_vector_type(8))) unsigned short u16x8;
typedef __attribute__((ext_vector_type(4))) float f32x4;

__device__ __forceinline__ float b2f(unsigned short h) {
  return __uint_as_float((unsigned)h << 16);
}
__device__ __forceinline__ unsigned short f2b(float f) {
  unsigned u = __float_as_uint(f);
  return (unsigned short)((u + 0x7FFF + ((u >> 16) & 1)) >> 16);
}
__device__ __forceinline__ float blo(unsigned u) { return __uint_as_float(u << 16); }
__device__ __forceinline__ float bhi(unsigned u) { return __uint_as_float(u & 0xFFFF0000u); }
__device__ __forceinline__ unsigned pk(float lo, float hi) {
  return (unsigned)f2b(lo) | ((unsigned)f2b(hi) << 16);
}

// x (f32) -> xb (bf16 pairs, row-major [N][128])
__global__ __launch_bounds__(256) void xcast_kernel(const float2* __restrict__ x,
    ushort2* __restrict__ xb, int total2) {
  int i = blockIdx.x * 256 + threadIdx.x;
  if (i >= total2) return;
  float2 v = x[i];
  xb[i] = make_ushort2(f2b(v.x), f2b(v.y));
}

// Wtb[s][n][k] (bf16, transposed weights) for the 1+2*NCv GEMM stages; bs = Σ b_i.
__global__ __launch_bounds__(256) void wcast_kernel(const float* __restrict__ W,
    const float* __restrict__ b, unsigned short* __restrict__ Wtb,
    float* __restrict__ bs, int KK, int NCv) {
  int p = blockIdx.x * 256 + threadIdx.x;
  const int stages = 1 + 2 * NCv;
  if (p < stages * CDIM * CDIM) {
    int s = p >> 14;
    int nk = p & 16383;
    int n = nk >> 7, k = nk & 127;
    float v;
    if (s == 0) {
      v = 0.f;
      for (int i = 0; i < NCv; ++i)
        v += W[(size_t)i * KK * CDIM * CDIM + (size_t)k * CDIM + n];
    } else {
      int i, kk;
      if (s & 1) { i = (s - 1) >> 1; kk = 1; }
      else       { i = (s >> 1) - 1; kk = 2; }
      v = W[(size_t)i * KK * CDIM * CDIM + (size_t)kk * CDIM * CDIM + (size_t)k * CDIM + n];
    }
    Wtb[p] = f2b(v);
  }
  if (p < CDIM) {
    float s = 0.f;
    for (int i = 0; i < NCv; ++i) s += b[i * CDIM + p];
    bs[p] = s;
  }
}

// partition edges into fixed-capacity (conv,bucket) slots.
// D record: (src u16, dst u16, w bf16, 0). S record: (src u16, w bf16).
__global__ __launch_bounds__(256) void partition_kernel(const int* __restrict__ ei,
    const float* __restrict__ ew, int* __restrict__ cntD, int* __restrict__ cntS,
    ushort4* __restrict__ Dfix, ushort2* __restrict__ Sfix, int E, int CE, int P,
    int NCv, int nr, int cap) {
  __shared__ int ld[MAXNR], ls[MAXNR], cd[MAXNR], cs[MAXNR];
  int conv = blockIdx.x / P;
  int pck = blockIdx.x - conv * P;
  int e0 = pck * CE;
  int e1 = min(E, e0 + CE);
  int t = threadIdx.x;
  const int* srcv = ei + (size_t)conv * 2 * E;
  const int* dstv = srcv + E;
  const float* w = ew + (size_t)conv * E;
  if (t < MAXNR) { ld[t] = 0; ls[t] = 0; }
  __syncthreads();
  for (int e = e0 + t; e < e1; e += 256) {
    atomicAdd(&ld[dstv[e] >> RSH], 1);
    atomicAdd(&ls[srcv[e] >> RSH], 1);
  }
  __syncthreads();
  if (t < nr) {
    cd[t] = ld[t] ? atomicAdd(&cntD[conv * nr + t], ld[t]) : 0;
    cs[t] = ls[t] ? atomicAdd(&cntS[conv * nr + t], ls[t]) : 0;
  }
  __syncthreads();
  for (int e = e0 + t; e < e1; e += 256) {
    int s = srcv[e], d = dstv[e];
    unsigned short wb = f2b(w[e]);
    int bd = d >> RSH, bs_ = s >> RSH;
    int pd = atomicAdd(&cd[bd], 1);
    Dfix[((size_t)(conv * nr + bd)) * cap + pd] =
        make_ushort4((unsigned short)s, (unsigned short)d, wb, 0);
    int ps = atomicAdd(&cs[bs_], 1);
    Sfix[((size_t)(conv * nr + bs_)) * cap + ps] =
        make_ushort2((unsigned short)s, wb);
  }
}

// tiny per-conv exclusive scan of bucket counts -> CSR bucket bases
__global__ __launch_bounds__(64) void count_scan(const int* __restrict__ cntD,
    int* __restrict__ basesD, int NCv, int nr) {
  int conv = threadIdx.x;
  if (conv >= NCv) return;
  int acc = 0;
  for (int b = 0; b < nr; ++b) {
    basesD[conv * nr + b] = acc;
    acc += cntD[conv * nr + b];
  }
}

// per (conv, bucket): LDS fine hist + deg; block scan; write row_ptr/diag/CSR.
__global__ __launch_bounds__(512) void finalize_kernel(const ushort4* __restrict__ Dfix,
    const ushort2* __restrict__ Sfix, const int* __restrict__ cntD,
    const int* __restrict__ cntS, const int* __restrict__ basesD,
    int* __restrict__ row_ptr, float* __restrict__ diag, ushort2* __restrict__ srcw,
    int E, int N, int NCv, int nr, int cap) {
  __shared__ unsigned int hist[RANGE];
  __shared__ float fdeg[RANGE];
  __shared__ unsigned int wls[8];
  int conv = blockIdx.x / nr;
  int b = blockIdx.x - conv * nr;
  int t = threadIdx.x;
  hist[t] = 0u; fdeg[t] = 0.f;
  __syncthreads();
  const ushort4* Dc = Dfix + ((size_t)(conv * nr + b)) * cap;
  const ushort2* Sc = Sfix + ((size_t)(conv * nr + b)) * cap;
  int nd = cntD[conv * nr + b];
  int ns = cntS[conv * nr + b];
  int db0 = basesD[conv * nr + b];
  for (int i = t; i < nd; i += 512)
    atomicAdd(&hist[Dc[i].y & (RANGE - 1)], 1u);
  for (int i = t; i < ns; i += 512) {
    ushort2 r = Sc[i];
    atomicAdd(&fdeg[r.x & (RANGE - 1)], b2f(r.y));
  }
  __syncthreads();
  unsigned int v = hist[t];
  int lane = t & 63, wid = t >> 6;
  unsigned int incl = v;
  #pragma unroll
  for (int off = 1; off < 64; off <<= 1) {
    unsigned int tmp = __shfl_up((int)incl, off, 64);
    if (lane >= off) incl += tmp;
  }
  if (lane == 63) wls[wid] = incl;
  __syncthreads();
  if (wid == 0) {
    unsigned int x = (lane < 8) ? wls[lane] : 0u;
    #pragma unroll
    for (int off = 1; off < 8; off <<= 1) {
      unsigned int tmp = __shfl_up((int)x, off, 64);
      if (lane >= off) x += tmp;
    }
    if (lane < 8) wls[lane] = x;
  }
  __syncthreads();
  unsigned int excl = (wid ? wls[wid - 1] : 0u) + (incl - v);
  hist[t] = excl;
  __syncthreads();
  int n0 = b << RSH;
  int* rp = row_ptr + (size_t)conv * (N + 1);
  float* dg = diag + (size_t)conv * N;
  int n = n0 + t;
  if (n < N) {
    rp[n] = db0 + (int)excl;
    dg[n] = fdeg[t] - 1.0f;
  }
  if (b == nr - 1 && t == 0) rp[N] = E;
  __syncthreads();
  ushort2* swc = srcw + (size_t)conv * E;
  for (int i = t; i < nd; i += 512) {
    ushort4 r = Dc[i];
    unsigned int pos = atomicAdd(&hist[r.y & (RANGE - 1)], 1u);
    swc[db0 + (int)pos] = make_ushort2(r.x, r.z);
  }
}

// Tx1_i = lhat_i(x), all convs. 4 rows/wave: 16 lanes x uint4 (8 ch) per row.
__global__ __launch_bounds__(256) void spmvA(const int* __restrict__ row_ptr,
    const ushort2* __restrict__ srcw, const float* __restrict__ diag,
    const uint4* __restrict__ xb, uint4* __restrict__ tx1b, int N, int E, int NCv) {
  int rg = blockIdx.x * 16 + ((int)threadIdx.x >> 4);
  if (rg >= NCv * N) return;
  int conv = rg / N;
  int row = rg - conv * N;
  const int* rp = row_ptr + (size_t)conv * (N + 1);
  const ushort2* sw = srcw + (size_t)conv * E;
  int c8 = threadIdx.x & 15;
  float d = diag[(size_t)conv * N + row];
  uint4 xv = xb[(size_t)row * 16 + c8];
  float a0 = d * blo(xv.x), a1 = d * bhi(xv.x);
  float a2 = d * blo(xv.y), a3 = d * bhi(xv.y);
  float a4 = d * blo(xv.z), a5 = d * bhi(xv.z);
  float a6 = d * blo(xv.w), a7 = d * bhi(xv.w);
  int e = rp[row], end = rp[row + 1];
  for (; e + 3 < end; e += 4) {
    ushort2 s0 = sw[e], s1 = sw[e + 1], s2 = sw[e + 2], s3 = sw[e + 3];
    uint4 v0 = xb[(size_t)s0.x * 16 + c8];
    uint4 v1 = xb[(size_t)s1.x * 16 + c8];
    uint4 v2 = xb[(size_t)s2.x * 16 + c8];
    uint4 v3 = xb[(size_t)s3.x * 16 + c8];
    float w0 = -b2f(s0.y), w1 = -b2f(s1.y), w2 = -b2f(s2.y), w3 = -b2f(s3.y);
    a0 = fmaf(w0, blo(v0.x), a0); a1 = fmaf(w0, bhi(v0.x), a1);
    a2 = fmaf(w0, blo(v0.y), a2); a3 = fmaf(w0, bhi(v0.y), a3);
    a4 = fmaf(w0, blo(v0.z), a4); a5 = fmaf(w0, bhi(v0.z), a5);
    a6 = fmaf(w0, blo(v0.w), a6); a7 = fmaf(w0, bhi(v0.w), a7);
    a0 = fmaf(w1, blo(v1.x), a0); a1 = fmaf(w1, bhi(v1.x), a1);
    a2 = fmaf(w1, blo(v1.y), a2); a3 = fmaf(w1, bhi(v1.y), a3);
    a4 = fmaf(w1, blo(v1.z), a4); a5 = fmaf(w1, bhi(v1.z), a5);
    a6 = fmaf(w1, blo(v1.w), a6); a7 = fmaf(w1, bhi(v1.w), a7);
    a0 = fmaf(w2, blo(v2.x), a0); a1 = fmaf(w2, bhi(v2.x), a1);
    a2 = fmaf(w2, blo(v2.y), a2); a3 = fmaf(w2, bhi(v2.y), a3);
    a4 = fmaf(w2, blo(v2.z), a4); a5 = fmaf(w2, bhi(v2.z), a5);
    a6 = fmaf(w2, blo(v2.w), a6); a7 = fmaf(w2, bhi(v2.w), a7);
    a0 = fmaf(w3, blo(v3.x), a0); a1 = fmaf(w3, bhi(v3.x), a1);
    a2 = fmaf(w3, blo(v3.y), a2); a3 = fmaf(w3, bhi(v3.y), a3);
    a4 = fmaf(w3, blo(v3.z), a4); a5 = fmaf(w3, bhi(v3.z), a5);
    a6 = fmaf(w3, blo(v3.w), a6); a7 = fmaf(w3, bhi(v3.w), a7);
  }
  for (; e < end; ++e) {
    ushort2 s0 = sw[e];
    uint4 v0 = xb[(size_t)s0.x * 16 + c8];
    float w0 = -b2f(s0.y);
    a0 = fmaf(w0, blo(v0.x), a0); a1 = fmaf(w0, bhi(v0.x), a1);
    a2 = fmaf(w0, blo(v0.y), a2); a3 = fmaf(w0, bhi(v0.y), a3);
    a4 = fmaf(w0, blo(v0.z), a4); a5 = fmaf(w0, bhi(v0.z), a5);
    a6 = fmaf(w0, blo(v0.w), a6); a7 = fmaf(w0, bhi(v0.w), a7);
  }
  tx1b[((size_t)conv * N + row) * 16 + c8] =
      make_uint4(pk(a0, a1), pk(a2, a3), pk(a4, a5), pk(a6, a7));
}

// Tx2_i = 2*lhat_i(Tx1_i) - x, all convs. Same 4 rows/wave layout.
__global__ __launch_bounds__(256) void spmvB_all(const int* __restrict__ row_ptr,
    const ushort2* __restrict__ srcw, const float* __restrict__ diag,
    const uint4* __restrict__ t1all, const uint4* __restrict__ xb,
    uint4* __restrict__ t2all, int N, int E, int NCv) {
  int rg = blockIdx.x * 16 + ((int)threadIdx.x >> 4);
  if (rg >= NCv * N) return;
  int conv = rg / N;
  int row = rg - conv * N;
  const int* rp = row_ptr + (size_t)conv * (N + 1);
  const ushort2* sw = srcw + (size_t)conv * E;
  const uint4* t1 = t1all + (size_t)conv * N * 16;
  int c8 = threadIdx.x & 15;
  float d = diag[(size_t)conv * N + row];
  uint4 tv = t1[(size_t)row * 16 + c8];
  float a0 = d * blo(tv.x), a1 = d * bhi(tv.x);
  float a2 = d * blo(tv.y), a3 = d * bhi(tv.y);
  float a4 = d * blo(tv.z), a5 = d * bhi(tv.z);
  float a6 = d * blo(tv.w), a7 = d * bhi(tv.w);
  int e = rp[row], end = rp[row + 1];
  for (; e + 3 < end; e += 4) {
    ushort2 s0 = sw[e], s1 = sw[e + 1], s2 = sw[e + 2], s3 = sw[e + 3];
    uint4 v0 = t1[(size_t)s0.x * 16 + c8];
    uint4 v1 = t1[(size_t)s1.x * 16 + c8];
    uint4 v2 = t1[(size_t)s2.x * 16 + c8];
    uint4 v3 = t1[(size_t)s3.x * 16 + c8];
    float w0 = -b2f(s0.y), w1 = -b2f(s1.y), w2 = -b2f(s2.y), w3 = -b2f(s3.y);
    a0 = fmaf(w0, blo(v0.x), a0); a1 = fmaf(w0, bhi(v0.x), a1);
    a2 = fmaf(w0, blo(v0.y), a2); a3 = fmaf(w0, bhi(v0.y), a3);
    a4 = fmaf(w0, blo(v0.z), a4); a5 = fmaf(w0, bhi(v0.z), a5);
    a6 = fmaf(w0, blo(v0.w), a6); a7 = fmaf(w0, bhi(v0.w), a7);
    a0 = fmaf(w1, blo(v1.x), a0); a1 = fmaf(w1, bhi(v1.x), a1);
    a2 = fmaf(w1, blo(v1.y), a2); a3 = fmaf(w1, bhi(v1.y), a3);
    a4 = fmaf(w1, blo(v1.z), a4); a5 = fmaf(w1, bhi(v1.z), a5);
    a6 = fmaf(w1, blo(v1.w), a6); a7 = fmaf(w1, bhi(v1.w), a7);
    a0 = fmaf(w2, blo(v2.x), a0); a1 = fmaf(w2, bhi(v2.x), a1);
    a2 = fmaf(w2, blo(v2.y), a2); a3 = fmaf(w2, bhi(v2.y), a3);
    a4 = fmaf(w2, blo(v2.z), a4); a5 = fmaf(w2, bhi(v2.z), a5);
    a6 = fmaf(w2, blo(v2.w), a6); a7 = fmaf(w2, bhi(v2.w), a7);
    a0 = fmaf(w3, blo(v3.x), a0); a1 = fmaf(w3, bhi(v3.x), a1);
    a2 = fmaf(w3, blo(v3.y), a2); a3 = fmaf(w3, bhi(v3.y), a3);
    a4 = fmaf(w3, blo(v3.z), a4); a5 = fmaf(w3, bhi(v3.z), a5);
    a6 = fmaf(w3, blo(v3.w), a6); a7 = fmaf(w3, bhi(v3.w), a7);
  }
  for (; e < end; ++e) {
    ushort2 s0 = sw[e];
    uint4 v0 = t1[(size_t)s0.x * 16 + c8];
    float w0 = -b2f(s0.y);
    a0 = fmaf(w0, blo(v0.x), a0); a1 = fmaf(w0, bhi(v0.x), a1);
    a2 = fmaf(w0, blo(v0.y), a2); a3 = fmaf(w0, bhi(v0.y), a3);
    a4 = fmaf(w0, blo(v0.z), a4); a5 = fmaf(w0, bhi(v0.z), a5);
    a6 = fmaf(w0, blo(v0.w), a6); a7 = fmaf(w0, bhi(v0.w), a7);
  }
  uint4 xv = xb[(size_t)row * 16 + c8];
  a0 = 2.f * a0 - blo(xv.x); a1 = 2.f * a1 - bhi(xv.x);
  a2 = 2.f * a2 - blo(xv.y); a3 = 2.f * a3 - bhi(xv.y);
  a4 = 2.f * a4 - blo(xv.z); a5 = 2.f * a5 - bhi(xv.z);
  a6 = 2.f * a6 - blo(xv.w); a7 = 2.f * a7 - bhi(xv.w);
  t2all[((size_t)conv * N + row) * 16 + c8] =
      make_uint4(pk(a0, a1), pk(a2, a3), pk(a4, a5), pk(a6, a7));
}

// MFMA GEMM with LDS double-buffered B (r9/r10, verified).
__global__ __launch_bounds__(256) void gemm_mfma(const unsigned short* __restrict__ xb,
    const unsigned short* __restrict__ t1all, const unsigned short* __restrict__ t2all,
    const unsigned short* __restrict__ Wtb, const float* __restrict__ bs,
    float* __restrict__ C, int N, int NCv) {
  __shared__ unsigned short Bl[2][CDIM * CDIM];
  const int t = threadIdx.x;
  const int wid = t >> 6;
  const int lane = t & 63;
  const int lr = lane & 15;
  const int lk = lane >> 4;
  const int r0 = blockIdx.x * 64 + wid * 16;
  const int stages = 1 + 2 * NCv;

  const int srow0 = t >> 4;
  const int wslot = t & 15;
  const int gslot = (t & 15) ^ ((t >> 4) & 7);

  f32x4 acc[8];
  #pragma unroll
  for (int nt = 0; nt < 8; ++nt) acc[nt] = (f32x4){0.f, 0.f, 0.f, 0.f};

  int ra = r0 + lr;
  ra = ra < N ? ra : N - 1;

  auto aptr = [&](int s) -> const unsigned short* {
    if (s == 0) return xb;
    if (s & 1) return t1all + (size_t)((s - 1) >> 1) * (size_t)N * CDIM;
    return t2all + (size_t)((s >> 1) - 1) * (size_t)N * CDIM;
  };

  u16x8 stg[8];
  {
    const unsigned short* Ws = Wtb;
    #pragma unroll
    for (int i = 0; i < 8; ++i)
      stg[i] = *(const u16x8*)(Ws + (size_t)(srow0 + i * 16) * CDIM + gslot * 8);
    #pragma unroll
    for (int i = 0; i < 8; ++i)
      *(u16x8*)(&Bl[0][(srow0 + i * 16) * CDIM + wslot * 8]) = stg[i];
  }
  bf16x8 aC[4], aN[4];
  {
    const unsigned short* A0 = aptr(0) + (size_t)ra * CDIM;
    #pragma unroll
    for (int kq = 0; kq < 4; ++kq)
      aC[kq] = *(const bf16x8*)(A0 + kq * 32 + lk * 8);
  }

  for (int s = 0; s < stages; ++s) {
    const int nb = s & 1;
    if (s + 1 < stages) {
      const unsigned short* Ws = Wtb + (size_t)(s + 1) * CDIM * CDIM;
      #pragma unroll
      for (int i = 0; i < 8; ++i)
        stg[i] = *(const u16x8*)(Ws + (size_t)(srow0 + i * 16) * CDIM + gslot * 8);
      const unsigned short* An = aptr(s + 1) + (size_t)ra * CDIM;
      #pragma unroll
      for (int kq = 0; kq < 4; ++kq)
        aN[kq] = *(const bf16x8*)(An + kq * 32 + lk * 8);
    }
    __syncthreads();
    #pragma unroll
    for (int nt = 0; nt < 8; ++nt) {
      const int row = nt * 16 + lr;
      const unsigned short* Bb = &Bl[nb][row * CDIM];
      #pragma unroll
      for (int kq = 0; kq < 4; ++kq) {
        const bf16x8 bf = *(const bf16x8*)(Bb + (((kq * 4 + lk) ^ (lr & 7)) * 8));
        acc[nt] = __builtin_amdgcn_mfma_f32_16x16x32_bf16(aC[kq], bf, acc[nt], 0, 0, 0);
      }
    }
    if (s + 1 < stages) {
      #pragma unroll
      for (int i = 0; i < 8; ++i)
        *(u16x8*)(&Bl[nb ^ 1][(srow0 + i * 16) * CDIM + wslot * 8]) = stg[i];
      #pragma unroll
      for (int kq = 0; kq < 4; ++kq) aC[kq] = aN[kq];
    }
  }

  const int orow = r0 + lk * 4;
  #pragma unroll
  for (int nt = 0; nt < 8; ++nt) {
    int col = nt * 16 + lr;
    float bb = bs[col];
    #pragma unroll
    for (int reg = 0; reg < 4; ++reg) {
      int r = orow + reg;
      if (r < N) C[(size_t)r * CDIM + col] = acc[nt][reg] + bb;
    }
  }
}

extern "C" void kernel_launch(void* const* d_in, const int* in_sizes, int n_in,
                              void* d_out, int out_size, void* d_ws, size_t ws_size,
                              hipStream_t stream) {
  const float* x  = (const float*)d_in[0];
  const int*   ei = (const int*)d_in[1];    // [NC, 2, E] int32
  const float* ew = (const float*)d_in[2];  // [NC, E]
  const float* W  = (const float*)d_in[3];  // [NC, K, 128, 128]
  const float* b  = (const float*)d_in[4];  // [NC, 128]

  const int Nn  = in_sizes[0] / CDIM;
  const int NCv = in_sizes[4] / CDIM;
  const int E   = in_sizes[2] / NCv;
  const int KK  = in_sizes[3] / (NCv * CDIM * CDIM);
  const int stages = 1 + 2 * NCv;
  const int nr = (Nn + RANGE - 1) / RANGE;
  const int cap = (((E + nr - 1) / nr) * 7 / 5 + 63) & ~63;  // 1.4x mean

  char* p = (char*)d_ws;
  auto take = [&](size_t bytes) { char* q = p; p += (bytes + 255) & ~(size_t)255; return q; };
  float* diag    = (float*)take((size_t)NCv * Nn * 4);
  int*   row_ptr = (int*)take((size_t)NCv * (Nn + 1) * 4);
  int*   cntD    = (int*)take((size_t)2 * NCv * nr * 4);  // cntD | cntS contiguous
  int*   cntS    = cntD + (size_t)NCv * nr;
  int*   basesD  = (int*)take((size_t)NCv * nr * 4);
  unsigned short* Wtb = (unsigned short*)take((size_t)stages * CDIM * CDIM * 2);
  float* bs      = (float*)take(CDIM * 4);
  ushort2* xb    = (ushort2*)take((size_t)Nn * 64 * 4);
  ushort2* tx1b  = (ushort2*)take((size_t)NCv * Nn * 64 * 4);
  // tx2b aliased with the transient fixed-cap bucket buffers (dead after finalize)
  size_t D_bytes  = ((size_t)NCv * nr * cap * 8 + 255) & ~(size_t)255;
  size_t S_bytes  = ((size_t)NCv * nr * cap * 4 + 255) & ~(size_t)255;
  size_t tx2_bytes = (size_t)NCv * Nn * 64 * 4;
  size_t big_bytes = D_bytes + S_bytes > tx2_bytes ? D_bytes + S_bytes : tx2_bytes;
  char* big = take(big_bytes);
  ushort2* tx2b = (ushort2*)big;
  ushort4* Dfix = (ushort4*)big;
  ushort2* Sfix = (ushort2*)(big + D_bytes);
  ushort2* srcw = (ushort2*)take((size_t)NCv * E * 4);

  hipMemsetAsync(cntD, 0, (size_t)2 * NCv * nr * 4, stream);  // exact region

  xcast_kernel<<<(Nn * 64 + 255) / 256, 256, 0, stream>>>(
      (const float2*)x, xb, Nn * 64);
  wcast_kernel<<<(stages * CDIM * CDIM + 255) / 256, 256, 0, stream>>>(
      W, b, Wtb, bs, KK, NCv);

  const int P = 256;
  const int CE = (E + P - 1) / P;
  partition_kernel<<<NCv * P, 256, 0, stream>>>(ei, ew, cntD, cntS, Dfix, Sfix,
                                                E, CE, P, NCv, nr, cap);
  count_scan<<<1, 64, 0, stream>>>(cntD, basesD, NCv, nr);
  finalize_kernel<<<NCv * nr, 512, 0, stream>>>(Dfix, Sfix, cntD, cntS, basesD,
                                                row_ptr, diag, srcw, E, Nn,
                                                NCv, nr, cap);

  spmvA<<<(NCv * Nn + 15) / 16, 256, 0, stream>>>(row_ptr, srcw, diag,
      (const uint4*)xb, (uint4*)tx1b, Nn, E, NCv);
  spmvB_all<<<(NCv * Nn + 15) / 16, 256, 0, stream>>>(row_ptr, srcw, diag,
      (const uint4*)tx1b, (const uint4*)xb, (uint4*)tx2b, Nn, E, NCv);

  gemm_mfma<<<(Nn + 63) / 64, 256, 0, stream>>>(
      (const unsigned short*)xb, (const unsigned short*)tx1b,
      (const unsigned short*)tx2b, Wtb, bs, (float*)d_out, Nn, NCv);
}